// Round 12
// baseline (70.271 us; speedup 1.0000x reference)
//
#include <hip/hip_runtime.h>

#define IN_F 128
#define OUT_F 128
#define BKLOG 5
#define BKN 32            // nodes per bucket
#define CAP 1024          // fixed slot capacity per bucket (exp ~512)
#define SLOTS 56          // edge slots per node in LDS
#define CHUNK 2048        // edges per scatter block (391 scatter blocks)
#define SCT 512           // threads per fused block

typedef __attribute__((ext_vector_type(8))) short short8v;
typedef __attribute__((ext_vector_type(4))) float float4v;

static __device__ __forceinline__ unsigned f2bf(float x) {
    unsigned b = __float_as_uint(x);
    return (b + 0x7FFFu + ((b >> 16) & 1u)) >> 16;   // RNE
}
static __device__ __forceinline__ float bfLo(unsigned u) { return __uint_as_float(u << 16); }
static __device__ __forceinline__ float bfHi(unsigned u) { return __uint_as_float(u & 0xFFFF0000u); }

static __device__ __forceinline__ void edge_fma(float ww, uint4 vv, float* a) {
    a[0] = fmaf(ww, bfLo(vv.x), a[0]); a[1] = fmaf(ww, bfHi(vv.x), a[1]);
    a[2] = fmaf(ww, bfLo(vv.y), a[2]); a[3] = fmaf(ww, bfHi(vv.y), a[3]);
    a[4] = fmaf(ww, bfLo(vv.z), a[4]); a[5] = fmaf(ww, bfHi(vv.z), a[5]);
    a[6] = fmaf(ww, bfLo(vv.w), a[6]); a[7] = fmaf(ww, bfHi(vv.w), a[7]);
}

// ---------------- prep: W^T -> bf16 (Wt[c][k]) + zero bucket cursors ----------------
__global__ __launch_bounds__(256) void prep_kernel(const float* __restrict__ W,
                                                   unsigned short* __restrict__ Wt,
                                                   int* __restrict__ gcur, int NBK)
{
    const int b = blockIdx.x;
    if (b < 64) {
        int i = b * 256 + threadIdx.x;
        int k = i >> 7, c = i & 127;
        Wt[c * 128 + k] = (unsigned short)f2bf(W[i]);
    } else {
        for (int i = threadIdx.x; i <= NBK; i += 256) gcur[i] = 0;
    }
}

// ---------------- fused: scatter blocks [0,NCH) + gemm blocks [NCH, NCH+GB) ----------------
__global__ __launch_bounds__(SCT) void fused_sg(
    const int* __restrict__ row, const int* __restrict__ col,
    const float* __restrict__ ew, int* __restrict__ gcur,
    uint2* __restrict__ bucket, uint2* __restrict__ ovf, int E, int NBK, int NCH,
    const float* __restrict__ A, const unsigned short* __restrict__ Wt,
    unsigned short* __restrict__ Cb, int nrows)
{
    __shared__ __align__(16) char ldsraw[2 * 128 * 136 * 2];   // 69632 B

    const int t = threadIdx.x;

    if (blockIdx.x < (unsigned)NCH) {
        // ---------------- scatter role ----------------
        int* h = (int*)ldsraw;                 // 2048 bucket counters
        const int base = blockIdx.x * CHUNK;
        const int lim  = min(CHUNK, E - base);

        for (int i = t; i < 2048; i += SCT) h[i] = 0;
        __syncthreads();

        int   rc[4]; float wc[4]; int cc[4];
#pragma unroll
        for (int k = 0; k < 4; ++k) {
            int i = t + k * SCT;
            if (i < lim) {
                rc[k] = row[base + i];
                wc[k] = ew[base + i];
                cc[k] = col[base + i];
                atomicAdd(&h[rc[k] >> BKLOG], 1);
            } else rc[k] = -1;
        }
        __syncthreads();

        for (int i = t; i < NBK; i += SCT) {
            int c = h[i];
            if (c) h[i] = atomicAdd(&gcur[i], c);
        }
        __syncthreads();

#pragma unroll
        for (int k = 0; k < 4; ++k) {
            if (rc[k] >= 0) {
                int r = rc[k];
                int b = r >> BKLOG;
                int p = atomicAdd(&h[b], 1);
                uint2 rec;
                rec.x = __float_as_uint(wc[k]);
                if (p < CAP) {
                    rec.y = ((unsigned)(r & (BKN - 1)) << 16) | (unsigned)cc[k];
                    bucket[(size_t)b * CAP + p] = rec;
                } else {
                    int q = atomicAdd(&gcur[NBK], 1);
                    rec.y = ((unsigned)r << 16) | (unsigned)cc[k];   // full node id
                    ovf[q] = rec;
                }
            }
        }
    } else {
        // ---------------- gemm role: 128 rows, 8 waves ----------------
        typedef unsigned short ushort136[136];
        ushort136* Al = (ushort136*)ldsraw;                      // [128][136]
        ushort136* Wl = (ushort136*)(ldsraw + 128 * 136 * 2);    // [128][136]
        const int rowBase = (blockIdx.x - NCH) * 128;

#pragma unroll
        for (int i = 0; i < 4; ++i) {               // W^T: 2048 uint4
            int q  = t + i * SCT;
            int c  = q >> 4;
            int kb = (q & 15) * 8;
            *(uint4*)(&Wl[c][kb]) = *(const uint4*)(Wt + c * 128 + kb);
        }
#pragma unroll
        for (int i = 0; i < 8; ++i) {               // A: 4096 float4 -> bf16
            int q  = t + i * SCT;
            int r  = q >> 5;
            int k4 = (q & 31) * 4;
            int gr = rowBase + r;
            if (gr >= nrows) gr = nrows - 1;
            float4 v = *(const float4*)(A + (size_t)gr * IN_F + k4);
            uint2 pk;
            pk.x = f2bf(v.x) | (f2bf(v.y) << 16);
            pk.y = f2bf(v.z) | (f2bf(v.w) << 16);
            *(uint2*)(&Al[r][k4]) = pk;
        }
        __syncthreads();

        const int w    = t >> 6;           // 0..7
        const int lane = t & 63;
        const int rb   = w * 16;
        const int m    = lane & 15;
        const int kg   = (lane >> 4) * 8;

        float4v acc[8];
#pragma unroll
        for (int n = 0; n < 8; ++n) acc[n] = (float4v){0.f, 0.f, 0.f, 0.f};

#pragma unroll
        for (int ks = 0; ks < 4; ++ks) {
            short8v a = *(const short8v*)(&Al[rb + m][ks * 32 + kg]);
#pragma unroll
            for (int n = 0; n < 8; ++n) {
                short8v bf = *(const short8v*)(&Wl[n * 16 + m][ks * 32 + kg]);
                acc[n] = __builtin_amdgcn_mfma_f32_16x16x32_bf16(a, bf, acc[n], 0, 0, 0);
            }
        }

        const int orow = rowBase + rb + (lane >> 4) * 4;
#pragma unroll
        for (int n = 0; n < 8; ++n) {
#pragma unroll
            for (int j = 0; j < 4; ++j) {
                int r = orow + j;
                if (r < nrows)
                    Cb[(size_t)r * OUT_F + n * 16 + m] = (unsigned short)f2bf(acc[n][j]);
            }
        }
    }
}

// ---------------- fused LDS-sort + SpMM(bf16 gather) + FiLM + PReLU ----------------
// one block (256 thr) per bucket of 32 nodes; quarter-wave (16 lanes) per node
__global__ __launch_bounds__(256) void spmm64_film(
    const int* __restrict__ gcur, const uint2* __restrict__ bucket,
    const uint2* __restrict__ ovf,
    const unsigned short* __restrict__ seqb, const int* __restrict__ ntype,
    const float* __restrict__ Wg, const float* __restrict__ bg,
    const float* __restrict__ Wb, const float* __restrict__ bb,
    const float* __restrict__ bias, const float* __restrict__ prelu,
    float* __restrict__ out, int N, int NBK)
{
    __shared__ uint2 slot[BKN * SLOTS];   // 14.3 KiB
    __shared__ int   bc[BKN];

    const int t = threadIdx.x;
    const int b = blockIdx.x;
    const uint2* breg = bucket + (size_t)b * CAP;
    const int total = gcur[b];
    const int inb   = min(total, CAP);

    if (t < BKN) bc[t] = 0;
    __syncthreads();

    for (int i = t; i < inb; i += 256) {
        uint2 rec = breg[i];
        int n = (rec.y >> 16) & (BKN - 1);
        int pos = atomicAdd(&bc[n], 1);
        if (pos < SLOTS) slot[n * SLOTS + pos] = rec;   // overflow -> exact fallback
    }
    __syncthreads();

    const int l  = t & 15;
    const int f0 = l * 8;
    const float sl = prelu[0];

    for (int g = 0; g < 2; ++g) {
        const int nl = g * 16 + (t >> 4);
        const int node = (b << BKLOG) + nl;
        if (node >= N) continue;

        const int deg = bc[nl];
        float a[8] = {0.f, 0.f, 0.f, 0.f, 0.f, 0.f, 0.f, 0.f};

        if (deg <= SLOTS) {
            const uint2* sp = &slot[nl * SLOTS];
            int j = 0;
            for (; j + 2 <= deg; j += 2) {
                uint2 r0 = sp[j], r1 = sp[j + 1];
                float w0 = __uint_as_float(r0.x);
                float w1 = __uint_as_float(r1.x);
                const uint4 v0 = *(const uint4*)(seqb + ((size_t)(r0.y & 0xFFFFu) << 7) + f0);
                const uint4 v1 = *(const uint4*)(seqb + ((size_t)(r1.y & 0xFFFFu) << 7) + f0);
                edge_fma(w0, v0, a);
                edge_fma(w1, v1, a);
            }
            if (j < deg) {
                uint2 r0 = sp[j];
                float w0 = __uint_as_float(r0.x);
                const uint4 v0 = *(const uint4*)(seqb + ((size_t)(r0.y & 0xFFFFu) << 7) + f0);
                edge_fma(w0, v0, a);
            }
        } else {
            for (int i = 0; i < inb; ++i) {
                uint2 rec = breg[i];
                if ((int)((rec.y >> 16) & (BKN - 1)) == nl) {
                    float w = __uint_as_float(rec.x);
                    const uint4 v = *(const uint4*)(seqb + ((size_t)(rec.y & 0xFFFFu) << 7) + f0);
                    edge_fma(w, v, a);
                }
            }
        }
        if (total > CAP) {
            const int novf = gcur[NBK];
            for (int i = 0; i < novf; ++i) {
                uint2 rec = ovf[i];
                if ((int)(rec.y >> 16) == node) {
                    float w = __uint_as_float(rec.x);
                    const uint4 v = *(const uint4*)(seqb + ((size_t)(rec.y & 0xFFFFu) << 7) + f0);
                    edge_fma(w, v, a);
                }
            }
        }

        const int tp = ntype[node];
        float4 g0 = *(const float4*)(Wg + tp * OUT_F + f0);
        float4 g1 = *(const float4*)(Wg + tp * OUT_F + f0 + 4);
        float4 h0 = *(const float4*)(bg + f0);
        float4 h1 = *(const float4*)(bg + f0 + 4);
        float4 p0 = *(const float4*)(Wb + tp * OUT_F + f0);
        float4 p1 = *(const float4*)(Wb + tp * OUT_F + f0 + 4);
        float4 q0 = *(const float4*)(bb + f0);
        float4 q1 = *(const float4*)(bb + f0 + 4);
        float4 s0 = *(const float4*)(bias + f0);
        float4 s1 = *(const float4*)(bias + f0 + 4);
        uint4  rs = *(const uint4*)(seqb + ((size_t)node << 7) + f0);

        float gg[8] = {g0.x + h0.x, g0.y + h0.y, g0.z + h0.z, g0.w + h0.w,
                       g1.x + h1.x, g1.y + h1.y, g1.z + h1.z, g1.w + h1.w};
        float pb[8] = {p0.x + q0.x + s0.x, p0.y + q0.y + s0.y, p0.z + q0.z + s0.z, p0.w + q0.w + s0.w,
                       p1.x + q1.x + s1.x, p1.y + q1.y + s1.y, p1.z + q1.z + s1.z, p1.w + q1.w + s1.w};
        float rv[8] = {bfLo(rs.x), bfHi(rs.x), bfLo(rs.y), bfHi(rs.y),
                       bfLo(rs.z), bfHi(rs.z), bfLo(rs.w), bfHi(rs.w)};
        float oo[8];
#pragma unroll
        for (int k = 0; k < 8; ++k) {
            float v = fmaf(gg[k], a[k], pb[k]) + rv[k];
            oo[k] = (v >= 0.f) ? v : sl * v;
        }
        *(float4*)(out + ((size_t)node << 7) + f0)     = make_float4(oo[0], oo[1], oo[2], oo[3]);
        *(float4*)(out + ((size_t)node << 7) + f0 + 4) = make_float4(oo[4], oo[5], oo[6], oo[7]);
    }
}

// ---------------- launch ----------------
extern "C" void kernel_launch(void* const* d_in, const int* in_sizes, int n_in,
                              void* d_out, int out_size, void* d_ws, size_t ws_size,
                              hipStream_t stream)
{
    const float* seq   = (const float*)d_in[0];
    const float* ew    = (const float*)d_in[1];
    const float* W_fc  = (const float*)d_in[2];
    const float* W_g   = (const float*)d_in[3];
    const float* b_g   = (const float*)d_in[4];
    const float* W_b   = (const float*)d_in[5];
    const float* b_b   = (const float*)d_in[6];
    const float* bias  = (const float*)d_in[7];
    const float* prelu = (const float*)d_in[8];
    const int*   erow  = (const int*)d_in[9];
    const int*   ecol  = (const int*)d_in[10];
    const int*   ntype = (const int*)d_in[11];
    const int N = in_sizes[11];
    const int E = in_sizes[1];
    const int NBK = (N + BKN - 1) >> BKLOG;            // 32-node buckets (~1564)
    const int NCH = (E + CHUNK - 1) / CHUNK;           // scatter chunks (391)
    const int GB  = (N + 127) / 128;                   // gemm blocks (391)

    char* ws = (char*)d_ws;
    size_t o = 0;
    unsigned short* seqb = (unsigned short*)(ws + o); o += (size_t)N * OUT_F * 2; o = (o + 15) & ~(size_t)15;
    unsigned short* Wt   = (unsigned short*)(ws + o); o += (size_t)IN_F * OUT_F * 2;
    int*   gcur = (int*)(ws + o);  o += 2049 * 4 + 12; o &= ~(size_t)15;
    uint2* bucket = (uint2*)(ws + o); o += (size_t)NBK * CAP * 8;
    uint2* ovf    = (uint2*)(ws + o); o += (size_t)E * 8;

    hipLaunchKernelGGL(prep_kernel, dim3(65), dim3(256), 0, stream, W_fc, Wt, gcur, NBK);
    hipLaunchKernelGGL(fused_sg, dim3(NCH + GB), dim3(SCT), 0, stream,
                       erow, ecol, ew, gcur, bucket, ovf, E, NBK, NCH,
                       seq, Wt, seqb, N);
    hipLaunchKernelGGL(spmm64_film, dim3(NBK), dim3(256), 0, stream,
                       gcur, bucket, ovf, seqb, ntype, W_g, b_g, W_b, b_b, bias, prelu,
                       (float*)d_out, N, NBK);
}

// Round 13
// 67.997 us; speedup vs baseline: 1.0334x; 1.0334x over previous
//
#include <hip/hip_runtime.h>

#define IN_F 128
#define OUT_F 128
#define BKLOG 5
#define BKN 32            // nodes per bucket
#define CAP 1024          // fixed slot capacity per bucket (exp ~512)
#define SLOTS 56          // edge slots per node in LDS
#define CHUNK 4096        // edges per scatter block (196 scatter blocks) -- R11 optimum
#define SCT 512           // threads per fused block

typedef __attribute__((ext_vector_type(8))) short short8v;
typedef __attribute__((ext_vector_type(4))) float float4v;

static __device__ __forceinline__ unsigned f2bf(float x) {
    unsigned b = __float_as_uint(x);
    return (b + 0x7FFFu + ((b >> 16) & 1u)) >> 16;   // RNE
}
static __device__ __forceinline__ float bfLo(unsigned u) { return __uint_as_float(u << 16); }
static __device__ __forceinline__ float bfHi(unsigned u) { return __uint_as_float(u & 0xFFFF0000u); }

static __device__ __forceinline__ void edge_fma(float ww, uint4 vv, float* a) {
    a[0] = fmaf(ww, bfLo(vv.x), a[0]); a[1] = fmaf(ww, bfHi(vv.x), a[1]);
    a[2] = fmaf(ww, bfLo(vv.y), a[2]); a[3] = fmaf(ww, bfHi(vv.y), a[3]);
    a[4] = fmaf(ww, bfLo(vv.z), a[4]); a[5] = fmaf(ww, bfHi(vv.z), a[5]);
    a[6] = fmaf(ww, bfLo(vv.w), a[6]); a[7] = fmaf(ww, bfHi(vv.w), a[7]);
}

// ---------------- fused: scatter blocks [0,NCH) + gemm blocks [NCH, NCH+GB) ----------------
// scatter: block-aggregated fixed-capacity bucket scatter (CHUNK edges/block)
// gemm:    MFMA bf16, 128 rows/block, 8 waves; stages W fp32 -> bf16^T in LDS itself
__global__ __launch_bounds__(SCT) void fused_sg(
    const int* __restrict__ row, const int* __restrict__ col,
    const float* __restrict__ ew, int* __restrict__ gcur,
    uint2* __restrict__ bucket, uint2* __restrict__ ovf, int E, int NBK, int NCH,
    const float* __restrict__ A, const float* __restrict__ W,
    unsigned short* __restrict__ Cb, int nrows)
{
    __shared__ __align__(16) char ldsraw[2 * 128 * 136 * 2];   // 69632 B

    const int t = threadIdx.x;

    if (blockIdx.x < (unsigned)NCH) {
        // ---------------- scatter role ----------------
        int* h = (int*)ldsraw;                 // 2048 bucket counters
        const int base = blockIdx.x * CHUNK;
        const int lim  = min(CHUNK, E - base);

        for (int i = t; i < 2048; i += SCT) h[i] = 0;
        __syncthreads();

        int   rc[8]; float wc[8]; int cc[8];
#pragma unroll
        for (int k = 0; k < 8; ++k) {
            int i = t + k * SCT;
            if (i < lim) {
                rc[k] = row[base + i];
                wc[k] = ew[base + i];
                cc[k] = col[base + i];
                atomicAdd(&h[rc[k] >> BKLOG], 1);
            } else rc[k] = -1;
        }
        __syncthreads();

        for (int i = t; i < NBK; i += SCT) {
            int c = h[i];
            if (c) h[i] = atomicAdd(&gcur[i], c);
        }
        __syncthreads();

#pragma unroll
        for (int k = 0; k < 8; ++k) {
            if (rc[k] >= 0) {
                int r = rc[k];
                int b = r >> BKLOG;
                int p = atomicAdd(&h[b], 1);
                uint2 rec;
                rec.x = __float_as_uint(wc[k]);
                if (p < CAP) {
                    rec.y = ((unsigned)(r & (BKN - 1)) << 16) | (unsigned)cc[k];
                    bucket[(size_t)b * CAP + p] = rec;
                } else {
                    int q = atomicAdd(&gcur[NBK], 1);
                    rec.y = ((unsigned)r << 16) | (unsigned)cc[k];   // full node id
                    ovf[q] = rec;
                }
            }
        }
    } else {
        // ---------------- gemm role: 128 rows, 8 waves ----------------
        typedef unsigned short ushort136[136];
        ushort136* Al = (ushort136*)ldsraw;                      // [128][136]
        ushort136* Wl = (ushort136*)(ldsraw + 128 * 136 * 2);    // [128][136] = W^T bf16
        const int rowBase = (blockIdx.x - NCH) * 128;

#pragma unroll
        for (int i = 0; i < 8; ++i) {               // W: 4096 float4, convert+transpose
            int q  = t + i * SCT;
            int k  = q >> 5;
            int c4 = (q & 31) * 4;
            float4 v = *(const float4*)(W + k * OUT_F + c4);
            Wl[c4 + 0][k] = (unsigned short)f2bf(v.x);
            Wl[c4 + 1][k] = (unsigned short)f2bf(v.y);
            Wl[c4 + 2][k] = (unsigned short)f2bf(v.z);
            Wl[c4 + 3][k] = (unsigned short)f2bf(v.w);
        }
#pragma unroll
        for (int i = 0; i < 8; ++i) {               // A: 4096 float4 -> bf16
            int q  = t + i * SCT;
            int r  = q >> 5;
            int k4 = (q & 31) * 4;
            int gr = rowBase + r;
            if (gr >= nrows) gr = nrows - 1;
            float4 v = *(const float4*)(A + (size_t)gr * IN_F + k4);
            uint2 pk;
            pk.x = f2bf(v.x) | (f2bf(v.y) << 16);
            pk.y = f2bf(v.z) | (f2bf(v.w) << 16);
            *(uint2*)(&Al[r][k4]) = pk;
        }
        __syncthreads();

        const int w    = t >> 6;           // 0..7
        const int lane = t & 63;
        const int rb   = w * 16;
        const int m    = lane & 15;
        const int kg   = (lane >> 4) * 8;

        float4v acc[8];
#pragma unroll
        for (int n = 0; n < 8; ++n) acc[n] = (float4v){0.f, 0.f, 0.f, 0.f};

#pragma unroll
        for (int ks = 0; ks < 4; ++ks) {
            short8v a = *(const short8v*)(&Al[rb + m][ks * 32 + kg]);
#pragma unroll
            for (int n = 0; n < 8; ++n) {
                short8v bf = *(const short8v*)(&Wl[n * 16 + m][ks * 32 + kg]);
                acc[n] = __builtin_amdgcn_mfma_f32_16x16x32_bf16(a, bf, acc[n], 0, 0, 0);
            }
        }

        const int orow = rowBase + rb + (lane >> 4) * 4;
#pragma unroll
        for (int n = 0; n < 8; ++n) {
#pragma unroll
            for (int j = 0; j < 4; ++j) {
                int r = orow + j;
                if (r < nrows)
                    Cb[(size_t)r * OUT_F + n * 16 + m] = (unsigned short)f2bf(acc[n][j]);
            }
        }
    }
}

// ---------------- fused LDS-sort + SpMM(bf16 gather) + FiLM + PReLU ----------------
// one block (256 thr) per bucket of 32 nodes; quarter-wave (16 lanes) per node
__global__ __launch_bounds__(256) void spmm64_film(
    const int* __restrict__ gcur, const uint2* __restrict__ bucket,
    const uint2* __restrict__ ovf,
    const unsigned short* __restrict__ seqb, const int* __restrict__ ntype,
    const float* __restrict__ Wg, const float* __restrict__ bg,
    const float* __restrict__ Wb, const float* __restrict__ bb,
    const float* __restrict__ bias, const float* __restrict__ prelu,
    float* __restrict__ out, int N, int NBK)
{
    __shared__ uint2 slot[BKN * SLOTS];   // 14.3 KiB
    __shared__ int   bc[BKN];

    const int t = threadIdx.x;
    const int b = blockIdx.x;
    const uint2* breg = bucket + (size_t)b * CAP;
    const int total = gcur[b];
    const int inb   = min(total, CAP);

    if (t < BKN) bc[t] = 0;
    __syncthreads();

    for (int i = t; i < inb; i += 256) {
        uint2 rec = breg[i];
        int n = (rec.y >> 16) & (BKN - 1);
        int pos = atomicAdd(&bc[n], 1);
        if (pos < SLOTS) slot[n * SLOTS + pos] = rec;   // overflow -> exact fallback
    }
    __syncthreads();

    const int l  = t & 15;
    const int f0 = l * 8;
    const float sl = prelu[0];

    for (int g = 0; g < 2; ++g) {
        const int nl = g * 16 + (t >> 4);
        const int node = (b << BKLOG) + nl;
        if (node >= N) continue;

        const int deg = bc[nl];
        float a[8] = {0.f, 0.f, 0.f, 0.f, 0.f, 0.f, 0.f, 0.f};

        if (deg <= SLOTS) {
            const uint2* sp = &slot[nl * SLOTS];
            int j = 0;
            for (; j + 2 <= deg; j += 2) {
                uint2 r0 = sp[j], r1 = sp[j + 1];
                float w0 = __uint_as_float(r0.x);
                float w1 = __uint_as_float(r1.x);
                const uint4 v0 = *(const uint4*)(seqb + ((size_t)(r0.y & 0xFFFFu) << 7) + f0);
                const uint4 v1 = *(const uint4*)(seqb + ((size_t)(r1.y & 0xFFFFu) << 7) + f0);
                edge_fma(w0, v0, a);
                edge_fma(w1, v1, a);
            }
            if (j < deg) {
                uint2 r0 = sp[j];
                float w0 = __uint_as_float(r0.x);
                const uint4 v0 = *(const uint4*)(seqb + ((size_t)(r0.y & 0xFFFFu) << 7) + f0);
                edge_fma(w0, v0, a);
            }
        } else {
            for (int i = 0; i < inb; ++i) {
                uint2 rec = breg[i];
                if ((int)((rec.y >> 16) & (BKN - 1)) == nl) {
                    float w = __uint_as_float(rec.x);
                    const uint4 v = *(const uint4*)(seqb + ((size_t)(rec.y & 0xFFFFu) << 7) + f0);
                    edge_fma(w, v, a);
                }
            }
        }
        if (total > CAP) {
            const int novf = gcur[NBK];
            for (int i = 0; i < novf; ++i) {
                uint2 rec = ovf[i];
                if ((int)(rec.y >> 16) == node) {
                    float w = __uint_as_float(rec.x);
                    const uint4 v = *(const uint4*)(seqb + ((size_t)(rec.y & 0xFFFFu) << 7) + f0);
                    edge_fma(w, v, a);
                }
            }
        }

        const int tp = ntype[node];
        float4 g0 = *(const float4*)(Wg + tp * OUT_F + f0);
        float4 g1 = *(const float4*)(Wg + tp * OUT_F + f0 + 4);
        float4 h0 = *(const float4*)(bg + f0);
        float4 h1 = *(const float4*)(bg + f0 + 4);
        float4 p0 = *(const float4*)(Wb + tp * OUT_F + f0);
        float4 p1 = *(const float4*)(Wb + tp * OUT_F + f0 + 4);
        float4 q0 = *(const float4*)(bb + f0);
        float4 q1 = *(const float4*)(bb + f0 + 4);
        float4 s0 = *(const float4*)(bias + f0);
        float4 s1 = *(const float4*)(bias + f0 + 4);
        uint4  rs = *(const uint4*)(seqb + ((size_t)node << 7) + f0);

        float gg[8] = {g0.x + h0.x, g0.y + h0.y, g0.z + h0.z, g0.w + h0.w,
                       g1.x + h1.x, g1.y + h1.y, g1.z + h1.z, g1.w + h1.w};
        float pb[8] = {p0.x + q0.x + s0.x, p0.y + q0.y + s0.y, p0.z + q0.z + s0.z, p0.w + q0.w + s0.w,
                       p1.x + q1.x + s1.x, p1.y + q1.y + s1.y, p1.z + q1.z + s1.z, p1.w + q1.w + s1.w};
        float rv[8] = {bfLo(rs.x), bfHi(rs.x), bfLo(rs.y), bfHi(rs.y),
                       bfLo(rs.z), bfHi(rs.z), bfLo(rs.w), bfHi(rs.w)};
        float oo[8];
#pragma unroll
        for (int k = 0; k < 8; ++k) {
            float v = fmaf(gg[k], a[k], pb[k]) + rv[k];
            oo[k] = (v >= 0.f) ? v : sl * v;
        }
        *(float4*)(out + ((size_t)node << 7) + f0)     = make_float4(oo[0], oo[1], oo[2], oo[3]);
        *(float4*)(out + ((size_t)node << 7) + f0 + 4) = make_float4(oo[4], oo[5], oo[6], oo[7]);
    }
}

// ---------------- launch ----------------
extern "C" void kernel_launch(void* const* d_in, const int* in_sizes, int n_in,
                              void* d_out, int out_size, void* d_ws, size_t ws_size,
                              hipStream_t stream)
{
    const float* seq   = (const float*)d_in[0];
    const float* ew    = (const float*)d_in[1];
    const float* W_fc  = (const float*)d_in[2];
    const float* W_g   = (const float*)d_in[3];
    const float* b_g   = (const float*)d_in[4];
    const float* W_b   = (const float*)d_in[5];
    const float* b_b   = (const float*)d_in[6];
    const float* bias  = (const float*)d_in[7];
    const float* prelu = (const float*)d_in[8];
    const int*   erow  = (const int*)d_in[9];
    const int*   ecol  = (const int*)d_in[10];
    const int*   ntype = (const int*)d_in[11];
    const int N = in_sizes[11];
    const int E = in_sizes[1];
    const int NBK = (N + BKN - 1) >> BKLOG;            // 32-node buckets (~1564)
    const int NCH = (E + CHUNK - 1) / CHUNK;           // scatter chunks (196)
    const int GB  = (N + 127) / 128;                   // gemm blocks (391)

    char* ws = (char*)d_ws;
    size_t o = 0;
    unsigned short* seqb = (unsigned short*)(ws + o); o += (size_t)N * OUT_F * 2; o = (o + 15) & ~(size_t)15;
    int*   gcur = (int*)(ws + o);  o += 2049 * 4 + 12; o &= ~(size_t)15;
    uint2* bucket = (uint2*)(ws + o); o += (size_t)NBK * CAP * 8;
    uint2* ovf    = (uint2*)(ws + o); o += (size_t)E * 8;

    hipMemsetAsync(gcur, 0, (size_t)(NBK + 1) * sizeof(int), stream);
    hipLaunchKernelGGL(fused_sg, dim3(NCH + GB), dim3(SCT), 0, stream,
                       erow, ecol, ew, gcur, bucket, ovf, E, NBK, NCH,
                       seq, W_fc, seqb, N);
    hipLaunchKernelGGL(spmm64_film, dim3(NBK), dim3(256), 0, stream,
                       gcur, bucket, ovf, seqb, ntype, W_g, b_g, W_b, b_b, bias, prelu,
                       (float*)d_out, N, NBK);
}

// Round 14
// 64.657 us; speedup vs baseline: 1.0868x; 1.0517x over previous
//
#include <hip/hip_runtime.h>

#define IN_F 128
#define OUT_F 128
#define BKLOG 5
#define BKN 32            // nodes per bucket
#define CAP 1024          // fixed slot capacity per bucket (exp ~512)
#define SLOTS 56          // edge slots per node in LDS
#define CHUNK 4096        // edges per scatter block
#define SCT 512           // threads per fused block

typedef __attribute__((ext_vector_type(8))) short short8v;
typedef __attribute__((ext_vector_type(4))) float float4v;

static __device__ __forceinline__ unsigned f2bf(float x) {
    unsigned b = __float_as_uint(x);
    return (b + 0x7FFFu + ((b >> 16) & 1u)) >> 16;   // RNE
}
static __device__ __forceinline__ float bfLo(unsigned u) { return __uint_as_float(u << 16); }
static __device__ __forceinline__ float bfHi(unsigned u) { return __uint_as_float(u & 0xFFFF0000u); }

static __device__ __forceinline__ void edge_fma(float ww, uint4 vv, float* a) {
    a[0] = fmaf(ww, bfLo(vv.x), a[0]); a[1] = fmaf(ww, bfHi(vv.x), a[1]);
    a[2] = fmaf(ww, bfLo(vv.y), a[2]); a[3] = fmaf(ww, bfHi(vv.y), a[3]);
    a[4] = fmaf(ww, bfLo(vv.z), a[4]); a[5] = fmaf(ww, bfHi(vv.z), a[5]);
    a[6] = fmaf(ww, bfLo(vv.w), a[6]); a[7] = fmaf(ww, bfHi(vv.w), a[7]);
}

// ---------------- prep: W^T -> bf16 (Wt[c][k]) + zero bucket cursors ----------------
__global__ __launch_bounds__(256) void prep_kernel(const float* __restrict__ W,
                                                   unsigned short* __restrict__ Wt,
                                                   int* __restrict__ gcur, int NBK)
{
    const int b = blockIdx.x;
    if (b < 64) {
        int i = b * 256 + threadIdx.x;
        int k = i >> 7, c = i & 127;
        Wt[c * 128 + k] = (unsigned short)f2bf(W[i]);
    } else {
        for (int i = threadIdx.x; i <= NBK; i += 256) gcur[i] = 0;
    }
}

// ---------------- fused: scatter blocks [0,NCH) + gemm blocks [NCH, NCH+GB) ----------------
__global__ __launch_bounds__(SCT) void fused_sg(
    const int* __restrict__ row, const int* __restrict__ col,
    const float* __restrict__ ew, int* __restrict__ gcur,
    uint2* __restrict__ bucket, uint2* __restrict__ ovf, int E, int NBK, int NCH,
    const float* __restrict__ A, const unsigned short* __restrict__ Wt,
    unsigned short* __restrict__ Cb, int nrows)
{
    __shared__ __align__(16) char ldsraw[2 * 128 * 136 * 2];   // 69632 B

    const int t = threadIdx.x;

    if (blockIdx.x < (unsigned)NCH) {
        // ---------------- scatter role ----------------
        int* h = (int*)ldsraw;                 // 2048 bucket counters
        const int base = blockIdx.x * CHUNK;
        const int lim  = min(CHUNK, E - base);

        for (int i = t; i < 2048; i += SCT) h[i] = 0;
        __syncthreads();

        int   rc[8]; float wc[8]; int cc[8];
#pragma unroll
        for (int k = 0; k < 8; ++k) {
            int i = t + k * SCT;
            if (i < lim) {
                rc[k] = row[base + i];
                wc[k] = ew[base + i];
                cc[k] = col[base + i];
                atomicAdd(&h[rc[k] >> BKLOG], 1);
            } else rc[k] = -1;
        }
        __syncthreads();

        for (int i = t; i < NBK; i += SCT) {
            int c = h[i];
            if (c) h[i] = atomicAdd(&gcur[i], c);
        }
        __syncthreads();

#pragma unroll
        for (int k = 0; k < 8; ++k) {
            if (rc[k] >= 0) {
                int r = rc[k];
                int b = r >> BKLOG;
                int p = atomicAdd(&h[b], 1);
                uint2 rec;
                rec.x = __float_as_uint(wc[k]);
                if (p < CAP) {
                    rec.y = ((unsigned)(r & (BKN - 1)) << 16) | (unsigned)cc[k];
                    bucket[(size_t)b * CAP + p] = rec;
                } else {
                    int q = atomicAdd(&gcur[NBK], 1);
                    rec.y = ((unsigned)r << 16) | (unsigned)cc[k];   // full node id
                    ovf[q] = rec;
                }
            }
        }
    } else {
        // ---------------- gemm role: 128 rows, 8 waves ----------------
        typedef unsigned short ushort136[136];
        ushort136* Al = (ushort136*)ldsraw;                      // [128][136]
        ushort136* Wl = (ushort136*)(ldsraw + 128 * 136 * 2);    // [128][136]
        const int rowBase = (blockIdx.x - NCH) * 128;

#pragma unroll
        for (int i = 0; i < 4; ++i) {               // W^T: 2048 uint4
            int q  = t + i * SCT;
            int c  = q >> 4;
            int kb = (q & 15) * 8;
            *(uint4*)(&Wl[c][kb]) = *(const uint4*)(Wt + c * 128 + kb);
        }
#pragma unroll
        for (int i = 0; i < 8; ++i) {               // A: 4096 float4 -> bf16
            int q  = t + i * SCT;
            int r  = q >> 5;
            int k4 = (q & 31) * 4;
            int gr = rowBase + r;
            if (gr >= nrows) gr = nrows - 1;
            float4 v = *(const float4*)(A + (size_t)gr * IN_F + k4);
            uint2 pk;
            pk.x = f2bf(v.x) | (f2bf(v.y) << 16);
            pk.y = f2bf(v.z) | (f2bf(v.w) << 16);
            *(uint2*)(&Al[r][k4]) = pk;
        }
        __syncthreads();

        const int w    = t >> 6;           // 0..7
        const int lane = t & 63;
        const int rb   = w * 16;
        const int m    = lane & 15;
        const int kg   = (lane >> 4) * 8;

        float4v acc[8];
#pragma unroll
        for (int n = 0; n < 8; ++n) acc[n] = (float4v){0.f, 0.f, 0.f, 0.f};

#pragma unroll
        for (int ks = 0; ks < 4; ++ks) {
            short8v a = *(const short8v*)(&Al[rb + m][ks * 32 + kg]);
#pragma unroll
            for (int n = 0; n < 8; ++n) {
                short8v bf = *(const short8v*)(&Wl[n * 16 + m][ks * 32 + kg]);
                acc[n] = __builtin_amdgcn_mfma_f32_16x16x32_bf16(a, bf, acc[n], 0, 0, 0);
            }
        }

        const int orow = rowBase + rb + (lane >> 4) * 4;
#pragma unroll
        for (int n = 0; n < 8; ++n) {
#pragma unroll
            for (int j = 0; j < 4; ++j) {
                int r = orow + j;
                if (r < nrows)
                    Cb[(size_t)r * OUT_F + n * 16 + m] = (unsigned short)f2bf(acc[n][j]);
            }
        }
    }
}

// ---------------- fused LDS-sort + SpMM(bf16 gather) + FiLM + PReLU ----------------
// one block (256 thr) per bucket of 32 nodes; quarter-wave (16 lanes) per node
__global__ __launch_bounds__(256) void spmm64_film(
    const int* __restrict__ gcur, const uint2* __restrict__ bucket,
    const uint2* __restrict__ ovf,
    const unsigned short* __restrict__ seqb, const int* __restrict__ ntype,
    const float* __restrict__ Wg, const float* __restrict__ bg,
    const float* __restrict__ Wb, const float* __restrict__ bb,
    const float* __restrict__ bias, const float* __restrict__ prelu,
    float* __restrict__ out, int N, int NBK)
{
    __shared__ uint2 slot[BKN * SLOTS];   // 14.3 KiB
    __shared__ int   bc[BKN];

    const int t = threadIdx.x;
    const int b = blockIdx.x;
    const uint2* breg = bucket + (size_t)b * CAP;
    const int total = gcur[b];
    const int inb   = min(total, CAP);

    if (t < BKN) bc[t] = 0;
    __syncthreads();

    for (int i = t; i < inb; i += 256) {
        uint2 rec = breg[i];
        int n = (rec.y >> 16) & (BKN - 1);
        int pos = atomicAdd(&bc[n], 1);
        if (pos < SLOTS) slot[n * SLOTS + pos] = rec;   // overflow -> exact fallback
    }
    __syncthreads();

    const int l  = t & 15;
    const int f0 = l * 8;
    const float sl = prelu[0];

    for (int g = 0; g < 2; ++g) {
        const int nl = g * 16 + (t >> 4);
        const int node = (b << BKLOG) + nl;
        if (node >= N) continue;

        const int deg = bc[nl];
        float a[8] = {0.f, 0.f, 0.f, 0.f, 0.f, 0.f, 0.f, 0.f};

        if (deg <= SLOTS) {
            const uint2* sp = &slot[nl * SLOTS];
            int j = 0;
            for (; j + 2 <= deg; j += 2) {
                uint2 r0 = sp[j], r1 = sp[j + 1];
                float w0 = __uint_as_float(r0.x);
                float w1 = __uint_as_float(r1.x);
                const uint4 v0 = *(const uint4*)(seqb + ((size_t)(r0.y & 0xFFFFu) << 7) + f0);
                const uint4 v1 = *(const uint4*)(seqb + ((size_t)(r1.y & 0xFFFFu) << 7) + f0);
                edge_fma(w0, v0, a);
                edge_fma(w1, v1, a);
            }
            if (j < deg) {
                uint2 r0 = sp[j];
                float w0 = __uint_as_float(r0.x);
                const uint4 v0 = *(const uint4*)(seqb + ((size_t)(r0.y & 0xFFFFu) << 7) + f0);
                edge_fma(w0, v0, a);
            }
        } else {
            for (int i = 0; i < inb; ++i) {
                uint2 rec = breg[i];
                if ((int)((rec.y >> 16) & (BKN - 1)) == nl) {
                    float w = __uint_as_float(rec.x);
                    const uint4 v = *(const uint4*)(seqb + ((size_t)(rec.y & 0xFFFFu) << 7) + f0);
                    edge_fma(w, v, a);
                }
            }
        }
        if (total > CAP) {
            const int novf = gcur[NBK];
            for (int i = 0; i < novf; ++i) {
                uint2 rec = ovf[i];
                if ((int)(rec.y >> 16) == node) {
                    float w = __uint_as_float(rec.x);
                    const uint4 v = *(const uint4*)(seqb + ((size_t)(rec.y & 0xFFFFu) << 7) + f0);
                    edge_fma(w, v, a);
                }
            }
        }

        const int tp = ntype[node];
        float4 g0 = *(const float4*)(Wg + tp * OUT_F + f0);
        float4 g1 = *(const float4*)(Wg + tp * OUT_F + f0 + 4);
        float4 h0 = *(const float4*)(bg + f0);
        float4 h1 = *(const float4*)(bg + f0 + 4);
        float4 p0 = *(const float4*)(Wb + tp * OUT_F + f0);
        float4 p1 = *(const float4*)(Wb + tp * OUT_F + f0 + 4);
        float4 q0 = *(const float4*)(bb + f0);
        float4 q1 = *(const float4*)(bb + f0 + 4);
        float4 s0 = *(const float4*)(bias + f0);
        float4 s1 = *(const float4*)(bias + f0 + 4);
        uint4  rs = *(const uint4*)(seqb + ((size_t)node << 7) + f0);

        float gg[8] = {g0.x + h0.x, g0.y + h0.y, g0.z + h0.z, g0.w + h0.w,
                       g1.x + h1.x, g1.y + h1.y, g1.z + h1.z, g1.w + h1.w};
        float pb[8] = {p0.x + q0.x + s0.x, p0.y + q0.y + s0.y, p0.z + q0.z + s0.z, p0.w + q0.w + s0.w,
                       p1.x + q1.x + s1.x, p1.y + q1.y + s1.y, p1.z + q1.z + s1.z, p1.w + q1.w + s1.w};
        float rv[8] = {bfLo(rs.x), bfHi(rs.x), bfLo(rs.y), bfHi(rs.y),
                       bfLo(rs.z), bfHi(rs.z), bfLo(rs.w), bfHi(rs.w)};
        float oo[8];
#pragma unroll
        for (int k = 0; k < 8; ++k) {
            float v = fmaf(gg[k], a[k], pb[k]) + rv[k];
            oo[k] = (v >= 0.f) ? v : sl * v;
        }
        *(float4*)(out + ((size_t)node << 7) + f0)     = make_float4(oo[0], oo[1], oo[2], oo[3]);
        *(float4*)(out + ((size_t)node << 7) + f0 + 4) = make_float4(oo[4], oo[5], oo[6], oo[7]);
    }
}

// ---------------- launch ----------------
extern "C" void kernel_launch(void* const* d_in, const int* in_sizes, int n_in,
                              void* d_out, int out_size, void* d_ws, size_t ws_size,
                              hipStream_t stream)
{
    const float* seq   = (const float*)d_in[0];
    const float* ew    = (const float*)d_in[1];
    const float* W_fc  = (const float*)d_in[2];
    const float* W_g   = (const float*)d_in[3];
    const float* b_g   = (const float*)d_in[4];
    const float* W_b   = (const float*)d_in[5];
    const float* b_b   = (const float*)d_in[6];
    const float* bias  = (const float*)d_in[7];
    const float* prelu = (const float*)d_in[8];
    const int*   erow  = (const int*)d_in[9];
    const int*   ecol  = (const int*)d_in[10];
    const int*   ntype = (const int*)d_in[11];
    const int N = in_sizes[11];
    const int E = in_sizes[1];
    const int NBK = (N + BKN - 1) >> BKLOG;            // 32-node buckets (~1564)
    const int NCH = (E + CHUNK - 1) / CHUNK;           // scatter chunks (196)
    const int GB  = (N + 127) / 128;                   // gemm blocks (391)

    char* ws = (char*)d_ws;
    size_t o = 0;
    unsigned short* seqb = (unsigned short*)(ws + o); o += (size_t)N * OUT_F * 2; o = (o + 15) & ~(size_t)15;
    unsigned short* Wt   = (unsigned short*)(ws + o); o += (size_t)IN_F * OUT_F * 2;
    int*   gcur = (int*)(ws + o);  o += 2049 * 4 + 12; o &= ~(size_t)15;
    uint2* bucket = (uint2*)(ws + o); o += (size_t)NBK * CAP * 8;
    uint2* ovf    = (uint2*)(ws + o); o += (size_t)E * 8;

    hipLaunchKernelGGL(prep_kernel, dim3(65), dim3(256), 0, stream, W_fc, Wt, gcur, NBK);
    hipLaunchKernelGGL(fused_sg, dim3(NCH + GB), dim3(SCT), 0, stream,
                       erow, ecol, ew, gcur, bucket, ovf, E, NBK, NCH,
                       seq, Wt, seqb, N);
    hipLaunchKernelGGL(spmm64_film, dim3(NBK), dim3(256), 0, stream,
                       gcur, bucket, ovf, seqb, ntype, W_g, b_g, W_b, b_b, bias, prelu,
                       (float*)d_out, N, NBK);
}